// Round 1
// baseline (856.678 us; speedup 1.0000x reference)
//
#include <hip/hip_runtime.h>

#define BB 2
#define NTOK 4096
#define DIM 128
#define INNER 256
#define HEADS 4
#define DH 64

// ---------------------------------------------------------------- kernel 1
// x + positional-encoding, then depthwise 3x3 (SAME, zero pad of x+pos)
__global__ __launch_bounds__(256) void k_pe_dw(const float* __restrict__ x,
    const float* __restrict__ pew, const float* __restrict__ peb,
    const float* __restrict__ dw, float* __restrict__ out) {
  int bc = blockIdx.x;              // b*128 + c
  int c = bc & (DIM - 1);
  float s0 = pew[c * 2 + 0] * (1.0f / 63.0f);
  float s1 = pew[c * 2 + 1] * (1.0f / 63.0f);
  float pb = peb[c];
  float w[9];
#pragma unroll
  for (int q = 0; q < 9; ++q) w[q] = dw[c * 9 + q];
  const float* xb = x + (size_t)bc * NTOK;
  float* ob = out + (size_t)bc * NTOK;
  for (int p = threadIdx.x; p < NTOK; p += 256) {
    int i = p >> 6, j = p & 63;
    float acc = 0.f;
#pragma unroll
    for (int di = 0; di < 3; ++di) {
      int ii = i + di - 1;
      if ((unsigned)ii < 64u) {
#pragma unroll
        for (int dj = 0; dj < 3; ++dj) {
          int jj = j + dj - 1;
          if ((unsigned)jj < 64u) {
            float xv = xb[ii * 64 + jj] + ii * s0 + jj * s1 + pb;
            acc += xv * w[di * 3 + dj];
          }
        }
      }
    }
    ob[p] = acc;
  }
}

// ---------------------------------------------------------------- kernel 5
// plain depthwise 3x3 (SAME), channels = cmask+1 (pow2)
__global__ __launch_bounds__(256) void k_dw(const float* __restrict__ x,
    const float* __restrict__ dw, float* __restrict__ out, int cmask) {
  int bc = blockIdx.x;
  int c = bc & cmask;
  float w[9];
#pragma unroll
  for (int q = 0; q < 9; ++q) w[q] = dw[c * 9 + q];
  const float* xb = x + (size_t)bc * NTOK;
  float* ob = out + (size_t)bc * NTOK;
  for (int p = threadIdx.x; p < NTOK; p += 256) {
    int i = p >> 6, j = p & 63;
    float acc = 0.f;
#pragma unroll
    for (int di = 0; di < 3; ++di) {
      int ii = i + di - 1;
      if ((unsigned)ii < 64u) {
#pragma unroll
        for (int dj = 0; dj < 3; ++dj) {
          int jj = j + dj - 1;
          if ((unsigned)jj < 64u) acc += xb[ii * 64 + jj] * w[di * 3 + dj];
        }
      }
    }
    ob[p] = acc;
  }
}

// ---------------------------------------------------------------- kernels 2/6
// C = W[M,K] @ Y[K,4096] per batch; 64x64 tiles, 4x4 micro.
// EPI 0: scatter o -> (q|k|v)[b*4+head][n][d], with o=(part<<8)|(d*4+head)
// EPI 1: linear store o0p[(b*M + o)*4096 + n]  (M = Mtiles*64)
template <int K, int EPI>
__global__ __launch_bounds__(256) void k_gemm(const float* __restrict__ W,
    const float* __restrict__ Y, float* __restrict__ o0p,
    float* __restrict__ o1p, float* __restrict__ o2p, int Mtiles) {
  __shared__ float Wl[64][68];
  __shared__ float Yl[64][68];
  int bid = blockIdx.x;
  int nt = bid & 63;
  int ot = (bid >> 6) % Mtiles;
  int b = bid / (64 * Mtiles);
  int t = threadIdx.x;
  int ty = t >> 4, tx = t & 15;
  const float* Wb = W + (size_t)(ot * 64) * K;
  const float* Yb = Y + (size_t)b * K * NTOK + nt * 64;
  float acc[4][4];
#pragma unroll
  for (int i = 0; i < 4; ++i)
#pragma unroll
    for (int j = 0; j < 4; ++j) acc[i][j] = 0.f;

  for (int k0 = 0; k0 < K; k0 += 64) {
#pragma unroll
    for (int u = 0; u < 4; ++u) {
      int f = t + 256 * u;
      int r = f >> 4, c4 = (f & 15) * 4;
      *(float4*)&Wl[r][c4] = *(const float4*)(Wb + (size_t)r * K + k0 + c4);
      *(float4*)&Yl[r][c4] = *(const float4*)(Yb + (size_t)(k0 + r) * NTOK + c4);
    }
    __syncthreads();
#pragma unroll 8
    for (int c = 0; c < 64; ++c) {
      float4 y4 = *(float4*)&Yl[c][tx * 4];
      float wv[4];
#pragma unroll
      for (int i = 0; i < 4; ++i) wv[i] = Wl[ty * 4 + i][c];
#pragma unroll
      for (int i = 0; i < 4; ++i) {
        acc[i][0] += wv[i] * y4.x;
        acc[i][1] += wv[i] * y4.y;
        acc[i][2] += wv[i] * y4.z;
        acc[i][3] += wv[i] * y4.w;
      }
    }
    __syncthreads();
  }

  int n = nt * 64 + tx * 4;
  if (EPI == 0) {
#pragma unroll
    for (int i = 0; i < 4; ++i) {
      int o = ot * 64 + ty * 4 + i;
      int part = o >> 8, rr = o & 255;
      int d = rr >> 2, head = rr & 3;
      float* dst = (part == 0) ? o0p : (part == 1) ? o1p : o2p;
      size_t base = ((size_t)(b * HEADS + head) * NTOK) * DH + d;
#pragma unroll
      for (int j = 0; j < 4; ++j) dst[base + (size_t)(n + j) * DH] = acc[i][j];
    }
  } else {
#pragma unroll
    for (int i = 0; i < 4; ++i) {
      int o = ot * 64 + ty * 4 + i;
      float* dst = o0p + ((size_t)(b * DIM + o)) * NTOK + n;
#pragma unroll
      for (int j = 0; j < 4; ++j) dst[j] = acc[i][j];
    }
  }
}

// ---------------------------------------------------------------- kernel 3
// per-head LayerNorm over d (64) for q and k, in place. wave per row.
__global__ __launch_bounds__(256) void k_lnqk(float* __restrict__ qh,
    float* __restrict__ kh, const float* __restrict__ nqw,
    const float* __restrict__ nqb, const float* __restrict__ nkw,
    const float* __restrict__ nkb) {
  int row = blockIdx.x * 4 + (threadIdx.x >> 6);  // 0 .. 65535
  int lane = threadIdx.x & 63;
  int buf = row >> 15;           // 0 = q, 1 = k
  int r = row & 32767;           // bh*4096 + n
  int head = (r >> 12) & 3;
  float* base = (buf ? kh : qh) + (size_t)r * DH;
  const float* wp = (buf ? nkw : nqw) + head * DH;
  const float* bp = (buf ? nkb : nqb) + head * DH;
  float v = base[lane];
  float s1 = v, s2 = v * v;
#pragma unroll
  for (int off = 1; off < 64; off <<= 1) {
    s1 += __shfl_xor(s1, off);
    s2 += __shfl_xor(s2, off);
  }
  float mu = s1 * (1.f / 64.f);
  float var = s2 * (1.f / 64.f) - mu * mu;
  base[lane] = (v - mu) * rsqrtf(var + 1e-6f) * wp[lane] + bp[lane];
}

// ---------------------------------------------------------------- kernel 4
// flash attention per (b*head, 64-query tile); online softmax; epilogue:
// out = attn@v + v, head-LN(no_w,no_b), scatter to channel layout [b][d*4+h][n]
__global__ __launch_bounds__(256) void k_attn(const float* __restrict__ qh,
    const float* __restrict__ kh, const float* __restrict__ vh,
    const float* __restrict__ now, const float* __restrict__ nob,
    float* __restrict__ att) {
  __shared__ float Ql[64][68], Kl[64][68], Vl[64][68];
  int bh = blockIdx.x, qt = blockIdx.y;
  int b = bh >> 2, head = bh & 3;
  int t = threadIdx.x;
  int ty = t >> 4, tx = t & 15;
  int r0 = ty * 4, d0 = tx * 4;
  const float* qb = qh + ((size_t)bh * NTOK + qt * 64) * DH;
#pragma unroll
  for (int u = 0; u < 4; ++u) {
    int f = t + 256 * u;
    int r = f >> 4, c4 = (f & 15) * 4;
    *(float4*)&Ql[r][c4] = *(const float4*)(qb + f * 4);
  }
  float m[4], l[4];
  float4 acc[4];
#pragma unroll
  for (int i = 0; i < 4; ++i) {
    m[i] = -1e30f;
    l[i] = 0.f;
    acc[i] = make_float4(0.f, 0.f, 0.f, 0.f);
  }
  for (int kt = 0; kt < 64; ++kt) {
    __syncthreads();  // prev PV done: Kl(P)/Vl free
    const float* kb = kh + ((size_t)bh * NTOK + kt * 64) * DH;
    const float* vb = vh + ((size_t)bh * NTOK + kt * 64) * DH;
#pragma unroll
    for (int u = 0; u < 4; ++u) {
      int f = t + 256 * u;
      int r = f >> 4, c4 = (f & 15) * 4;
      *(float4*)&Kl[r][c4] = *(const float4*)(kb + f * 4);
      *(float4*)&Vl[r][c4] = *(const float4*)(vb + f * 4);
    }
    __syncthreads();
    // S = 0.125 * Q K^T  (4x4 per thread)
    float s[4][4];
#pragma unroll
    for (int i = 0; i < 4; ++i)
#pragma unroll
      for (int j = 0; j < 4; ++j) s[i][j] = 0.f;
#pragma unroll
    for (int d4 = 0; d4 < 16; ++d4) {
      float4 qv[4], kv[4];
#pragma unroll
      for (int i = 0; i < 4; ++i) qv[i] = *(float4*)&Ql[r0 + i][d4 * 4];
#pragma unroll
      for (int j = 0; j < 4; ++j) kv[j] = *(float4*)&Kl[d0 + j][d4 * 4];
#pragma unroll
      for (int i = 0; i < 4; ++i)
#pragma unroll
        for (int j = 0; j < 4; ++j)
          s[i][j] += qv[i].x * kv[j].x + qv[i].y * kv[j].y +
                     qv[i].z * kv[j].z + qv[i].w * kv[j].w;
    }
    __syncthreads();  // all Kl reads done; Kl reusable for P
    // online softmax over this key tile (row stats shared across 16 tx lanes)
#pragma unroll
    for (int i = 0; i < 4; ++i) {
#pragma unroll
      for (int j = 0; j < 4; ++j) s[i][j] *= 0.125f;
      float rm = fmaxf(fmaxf(s[i][0], s[i][1]), fmaxf(s[i][2], s[i][3]));
      rm = fmaxf(rm, __shfl_xor(rm, 1));
      rm = fmaxf(rm, __shfl_xor(rm, 2));
      rm = fmaxf(rm, __shfl_xor(rm, 4));
      rm = fmaxf(rm, __shfl_xor(rm, 8));
      float mn = fmaxf(m[i], rm);
      float alpha = __expf(m[i] - mn);
      float rs = 0.f;
#pragma unroll
      for (int j = 0; j < 4; ++j) {
        float p = __expf(s[i][j] - mn);
        s[i][j] = p;
        rs += p;
      }
      rs += __shfl_xor(rs, 1);
      rs += __shfl_xor(rs, 2);
      rs += __shfl_xor(rs, 4);
      rs += __shfl_xor(rs, 8);
      l[i] = l[i] * alpha + rs;
      m[i] = mn;
      acc[i].x *= alpha; acc[i].y *= alpha; acc[i].z *= alpha; acc[i].w *= alpha;
#pragma unroll
      for (int j = 0; j < 4; ++j) Kl[r0 + i][d0 + j] = s[i][j];
    }
    __syncthreads();  // P visible
    // PV: acc[i] += sum_c P[r0+i][c] * V[c][d0..d0+3]
#pragma unroll 8
    for (int c = 0; c < 64; ++c) {
      float4 v4 = *(float4*)&Vl[c][d0];
#pragma unroll
      for (int i = 0; i < 4; ++i) {
        float p = Kl[r0 + i][c];
        acc[i].x += p * v4.x; acc[i].y += p * v4.y;
        acc[i].z += p * v4.z; acc[i].w += p * v4.w;
      }
    }
  }
  __syncthreads();
  // stash O = acc/l into Ql
#pragma unroll
  for (int i = 0; i < 4; ++i) {
    float inv = 1.0f / l[i];
    Ql[r0 + i][d0 + 0] = acc[i].x * inv;
    Ql[r0 + i][d0 + 1] = acc[i].y * inv;
    Ql[r0 + i][d0 + 2] = acc[i].z * inv;
    Ql[r0 + i][d0 + 3] = acc[i].w * inv;
  }
  __syncthreads();
  // out = O + v ; head-LN ; scatter to [b][d*4+head][n]
  int wv = t >> 6, lane = t & 63;
  const float* vq = vh + ((size_t)bh * NTOK + qt * 64) * DH;
  float wn = now[head * DH + lane], bn = nob[head * DH + lane];
  for (int r = wv; r < 64; r += 4) {
    float v = Ql[r][lane] + vq[r * DH + lane];
    float s1 = v, s2 = v * v;
#pragma unroll
    for (int off = 1; off < 64; off <<= 1) {
      s1 += __shfl_xor(s1, off);
      s2 += __shfl_xor(s2, off);
    }
    float mu = s1 * (1.f / 64.f);
    float var = s2 * (1.f / 64.f) - mu * mu;
    float y = (v - mu) * rsqrtf(var + 1e-6f) * wn + bn;
    att[((size_t)(b * INNER + lane * 4 + head)) * NTOK + qt * 64 + r] = y;
  }
}

// ---------------------------------------------------------------- kernel 7
// LayerNorm over 128 channels at each (b, n); write final output
__global__ __launch_bounds__(256) void k_ln2d(const float* __restrict__ pw,
    const float* __restrict__ lnw, const float* __restrict__ lnb,
    float* __restrict__ out) {
  __shared__ float sh1[4][64], sh2[4][64];
  int b = blockIdx.x >> 6, nt = blockIdx.x & 63;
  int ln = threadIdx.x & 63, part = threadIdx.x >> 6;
  int n = nt * 64 + ln;
  const float* base = pw + (size_t)b * DIM * NTOK + n;
  float a1 = 0.f, a2 = 0.f;
  for (int c = part * 32; c < part * 32 + 32; ++c) {
    float v = base[(size_t)c * NTOK];
    a1 += v;
    a2 += v * v;
  }
  sh1[part][ln] = a1;
  sh2[part][ln] = a2;
  __syncthreads();
  float s1 = sh1[0][ln] + sh1[1][ln] + sh1[2][ln] + sh1[3][ln];
  float s2 = sh2[0][ln] + sh2[1][ln] + sh2[2][ln] + sh2[3][ln];
  float mu = s1 * (1.f / 128.f);
  float var = s2 * (1.f / 128.f) - mu * mu;
  float ri = rsqrtf(var + 1e-6f);
  float* ob = out + (size_t)b * DIM * NTOK + n;
  for (int c = part * 32; c < part * 32 + 32; ++c) {
    float v = base[(size_t)c * NTOK];
    ob[(size_t)c * NTOK] = (v - mu) * ri * lnw[c] + lnb[c];
  }
}

// ----------------------------------------------------------------
extern "C" void kernel_launch(void* const* d_in, const int* in_sizes, int n_in,
                              void* d_out, int out_size, void* d_ws,
                              size_t ws_size, hipStream_t stream) {
  const float* x      = (const float*)d_in[0];
  const float* pe_w   = (const float*)d_in[1];
  const float* pe_b   = (const float*)d_in[2];
  const float* qkv_dw = (const float*)d_in[3];
  const float* qkv_pw = (const float*)d_in[4];
  const float* out_dw = (const float*)d_in[5];
  const float* out_pw = (const float*)d_in[6];
  const float* nq_w   = (const float*)d_in[7];
  const float* nq_b   = (const float*)d_in[8];
  const float* nk_w   = (const float*)d_in[9];
  const float* nk_b   = (const float*)d_in[10];
  const float* no_w   = (const float*)d_in[11];
  const float* no_b   = (const float*)d_in[12];
  const float* ln_w   = (const float*)d_in[13];
  const float* ln_b   = (const float*)d_in[14];

  float* ws = (float*)d_ws;
  float* dwy  = ws;                    // [2][128][4096]    1,048,576 f
  float* qhb  = ws + (1u << 20);       // [8][4096][64]     2,097,152 f
  float* khb  = qhb + (1u << 21);
  float* vhb  = khb + (1u << 21);
  float* att  = vhb + (1u << 21);      // [2][256][4096]    2,097,152 f
  float* dwy2 = qhb;                   // reuse (q dead after attention)
  float* pwout = dwy;                  // reuse (dwy dead after qkv gemm)
  float* outp = (float*)d_out;

  k_pe_dw<<<dim3(BB * DIM), dim3(256), 0, stream>>>(x, pe_w, pe_b, qkv_dw, dwy);
  k_gemm<128, 0><<<dim3(BB * 12 * 64), dim3(256), 0, stream>>>(
      qkv_pw, dwy, qhb, khb, vhb, 12);
  k_lnqk<<<dim3(16384), dim3(256), 0, stream>>>(qhb, khb, nq_w, nq_b, nk_w, nk_b);
  k_attn<<<dim3(8, 64), dim3(256), 0, stream>>>(qhb, khb, vhb, no_w, no_b, att);
  k_dw<<<dim3(BB * INNER), dim3(256), 0, stream>>>(att, out_dw, dwy2, INNER - 1);
  k_gemm<256, 1><<<dim3(BB * 2 * 64), dim3(256), 0, stream>>>(
      out_pw, dwy2, pwout, nullptr, nullptr, 2);
  k_ln2d<<<dim3(BB * 64), dim3(256), 0, stream>>>(pwout, ln_w, ln_b, outp);
}

// Round 2
// 287.268 us; speedup vs baseline: 2.9822x; 2.9822x over previous
//
#include <hip/hip_runtime.h>

#define BB 2
#define NTOK 4096
#define DIM 128
#define INNER 256
#define HEADS 4
#define DH 64

typedef __attribute__((ext_vector_type(8))) short bf16x8;
typedef __attribute__((ext_vector_type(16))) float f32x16;

__device__ inline unsigned f2bf1(float f) {
  union { float f; unsigned u; } a; a.f = f;
  return (a.u + 0x7fffu + ((a.u >> 16) & 1u)) >> 16;  // RNE
}
__device__ inline unsigned packbf(float lo, float hi) {
  return f2bf1(lo) | (f2bf1(hi) << 16);
}

// ---------------------------------------------------------------- kernel 1
// x + positional-encoding, then depthwise 3x3 (SAME, zero pad of x+pos)
__global__ __launch_bounds__(256) void k_pe_dw(const float* __restrict__ x,
    const float* __restrict__ pew, const float* __restrict__ peb,
    const float* __restrict__ dw, float* __restrict__ out) {
  int bc = blockIdx.x;              // b*128 + c
  int c = bc & (DIM - 1);
  float s0 = pew[c * 2 + 0] * (1.0f / 63.0f);
  float s1 = pew[c * 2 + 1] * (1.0f / 63.0f);
  float pb = peb[c];
  float w[9];
#pragma unroll
  for (int q = 0; q < 9; ++q) w[q] = dw[c * 9 + q];
  const float* xb = x + (size_t)bc * NTOK;
  float* ob = out + (size_t)bc * NTOK;
  for (int p = threadIdx.x; p < NTOK; p += 256) {
    int i = p >> 6, j = p & 63;
    float acc = 0.f;
#pragma unroll
    for (int di = 0; di < 3; ++di) {
      int ii = i + di - 1;
      if ((unsigned)ii < 64u) {
#pragma unroll
        for (int dj = 0; dj < 3; ++dj) {
          int jj = j + dj - 1;
          if ((unsigned)jj < 64u) {
            float xv = xb[ii * 64 + jj] + ii * s0 + jj * s1 + pb;
            acc += xv * w[di * 3 + dj];
          }
        }
      }
    }
    ob[p] = acc;
  }
}

// ---------------------------------------------------------------- kernel 5
__global__ __launch_bounds__(256) void k_dw(const float* __restrict__ x,
    const float* __restrict__ dw, float* __restrict__ out, int cmask) {
  int bc = blockIdx.x;
  int c = bc & cmask;
  float w[9];
#pragma unroll
  for (int q = 0; q < 9; ++q) w[q] = dw[c * 9 + q];
  const float* xb = x + (size_t)bc * NTOK;
  float* ob = out + (size_t)bc * NTOK;
  for (int p = threadIdx.x; p < NTOK; p += 256) {
    int i = p >> 6, j = p & 63;
    float acc = 0.f;
#pragma unroll
    for (int di = 0; di < 3; ++di) {
      int ii = i + di - 1;
      if ((unsigned)ii < 64u) {
#pragma unroll
        for (int dj = 0; dj < 3; ++dj) {
          int jj = j + dj - 1;
          if ((unsigned)jj < 64u) acc += xb[ii * 64 + jj] * w[di * 3 + dj];
        }
      }
    }
    ob[p] = acc;
  }
}

// ---------------------------------------------------------------- kernels 2/6
template <int K, int EPI>
__global__ __launch_bounds__(256) void k_gemm(const float* __restrict__ W,
    const float* __restrict__ Y, float* __restrict__ o0p,
    float* __restrict__ o1p, float* __restrict__ o2p, int Mtiles) {
  __shared__ float Wl[64][68];
  __shared__ float Yl[64][68];
  int bid = blockIdx.x;
  int nt = bid & 63;
  int ot = (bid >> 6) % Mtiles;
  int b = bid / (64 * Mtiles);
  int t = threadIdx.x;
  int ty = t >> 4, tx = t & 15;
  const float* Wb = W + (size_t)(ot * 64) * K;
  const float* Yb = Y + (size_t)b * K * NTOK + nt * 64;
  float acc[4][4];
#pragma unroll
  for (int i = 0; i < 4; ++i)
#pragma unroll
    for (int j = 0; j < 4; ++j) acc[i][j] = 0.f;

  for (int k0 = 0; k0 < K; k0 += 64) {
#pragma unroll
    for (int u = 0; u < 4; ++u) {
      int f = t + 256 * u;
      int r = f >> 4, c4 = (f & 15) * 4;
      *(float4*)&Wl[r][c4] = *(const float4*)(Wb + (size_t)r * K + k0 + c4);
      *(float4*)&Yl[r][c4] = *(const float4*)(Yb + (size_t)(k0 + r) * NTOK + c4);
    }
    __syncthreads();
#pragma unroll 8
    for (int c = 0; c < 64; ++c) {
      float4 y4 = *(float4*)&Yl[c][tx * 4];
      float wv[4];
#pragma unroll
      for (int i = 0; i < 4; ++i) wv[i] = Wl[ty * 4 + i][c];
#pragma unroll
      for (int i = 0; i < 4; ++i) {
        acc[i][0] += wv[i] * y4.x;
        acc[i][1] += wv[i] * y4.y;
        acc[i][2] += wv[i] * y4.z;
        acc[i][3] += wv[i] * y4.w;
      }
    }
    __syncthreads();
  }

  int n = nt * 64 + tx * 4;
  if (EPI == 0) {
#pragma unroll
    for (int i = 0; i < 4; ++i) {
      int o = ot * 64 + ty * 4 + i;
      int part = o >> 8, rr = o & 255;
      int d = rr >> 2, head = rr & 3;
      float* dst = (part == 0) ? o0p : (part == 1) ? o1p : o2p;
      size_t base = ((size_t)(b * HEADS + head) * NTOK) * DH + d;
#pragma unroll
      for (int j = 0; j < 4; ++j) dst[base + (size_t)(n + j) * DH] = acc[i][j];
    }
  } else {
#pragma unroll
    for (int i = 0; i < 4; ++i) {
      int o = ot * 64 + ty * 4 + i;
      float* dst = o0p + ((size_t)(b * DIM + o)) * NTOK + n;
#pragma unroll
      for (int j = 0; j < 4; ++j) dst[j] = acc[i][j];
    }
  }
}

// ---------------------------------------------------------------- kernel 3
__global__ __launch_bounds__(256) void k_lnqk(float* __restrict__ qh,
    float* __restrict__ kh, const float* __restrict__ nqw,
    const float* __restrict__ nqb, const float* __restrict__ nkw,
    const float* __restrict__ nkb) {
  int row = blockIdx.x * 4 + (threadIdx.x >> 6);  // 0 .. 65535
  int lane = threadIdx.x & 63;
  int buf = row >> 15;           // 0 = q, 1 = k
  int r = row & 32767;           // bh*4096 + n
  int head = (r >> 12) & 3;
  float* base = (buf ? kh : qh) + (size_t)r * DH;
  const float* wp = (buf ? nkw : nqw) + head * DH;
  const float* bp = (buf ? nkb : nqb) + head * DH;
  float v = base[lane];
  float s1 = v, s2 = v * v;
#pragma unroll
  for (int off = 1; off < 64; off <<= 1) {
    s1 += __shfl_xor(s1, off);
    s2 += __shfl_xor(s2, off);
  }
  float mu = s1 * (1.f / 64.f);
  float var = s2 * (1.f / 64.f) - mu * mu;
  base[lane] = (v - mu) * rsqrtf(var + 1e-6f) * wp[lane] + bp[lane];
}

// ---------------------------------------------------------------- kernel 4
// MFMA flash attention. Block = (bh, 128-q tile); 4 waves x 32 q each.
// Swapped operands: S^T = mfma(K, Q), O^T = mfma(V^T, P^T); lane owns one q.
// K / V^T tiles double-buffered bf16 in LDS, XOR swizzle ^((row&7)<<4).
// Epilogue: O/l + v skip, head-LN, scatter to [b][d*4+head][n].
__global__ __launch_bounds__(256, 1) void k_attn_mfma(
    const float* __restrict__ qh, const float* __restrict__ kh,
    const float* __restrict__ vh, const float* __restrict__ now,
    const float* __restrict__ nob, float* __restrict__ att) {
  __shared__ __align__(16) unsigned short smem[16384];  // 32KB: K[2],Vt[2] 8KB each
  __shared__ float nw[DH], nb[DH];
  const int bh = blockIdx.x >> 5;
  const int qt = blockIdx.x & 31;
  const int b = bh >> 2, head = bh & 3;
  const int t = threadIdx.x;
  const int w = t >> 6, l = t & 63;
  const int hi = l >> 5, lq = l & 31;
  const size_t bhb = (size_t)bh * NTOK * DH;

  if (t < DH) { nw[t] = now[head * DH + t]; nb[t] = nob[head * DH + t]; }

  // ---- stage Q (x0.125) bf16, swizzled rows of 64 bf16 (128B)
  {
    int rr = t >> 3, slot = t & 7;
#pragma unroll
    for (int pass = 0; pass < 4; ++pass) {
      int row = pass * 32 + rr;
      const float4* src =
          (const float4*)(qh + bhb + (size_t)(qt * 128 + row) * DH + slot * 8);
      float4 f0 = src[0], f1 = src[1];
      uint4 u;
      u.x = packbf(f0.x * 0.125f, f0.y * 0.125f);
      u.y = packbf(f0.z * 0.125f, f0.w * 0.125f);
      u.z = packbf(f1.x * 0.125f, f1.y * 0.125f);
      u.w = packbf(f1.z * 0.125f, f1.w * 0.125f);
      *(uint4*)&smem[row * 64 + 8 * (slot ^ (row & 7))] = u;
    }
  }
  __syncthreads();
  // Q B-frags: lane reads Q[w*32+lq][16ks+8hi .. +7]
  bf16x8 qf[4];
#pragma unroll
  for (int ks = 0; ks < 4; ++ks) {
    int row = w * 32 + lq;
    qf[ks] = *(bf16x8*)&smem[row * 64 + ((16 * ks + 8 * hi) ^ (8 * (row & 7)))];
  }
  __syncthreads();

  const int krr = t >> 3, kslot = t & 7;  // K staging coords
  const int vr_ = t & 63, vc = t >> 6;    // V staging coords
  float4 kr[4], vv4[4];

  // load tile 0 into regs
  {
    const float* kp = kh + bhb;
    const float* vp = vh + bhb;
#pragma unroll
    for (int pp = 0; pp < 2; ++pp) {
      const float4* s = (const float4*)(kp + (size_t)(pp * 32 + krr) * DH + kslot * 8);
      kr[2 * pp] = s[0];
      kr[2 * pp + 1] = s[1];
    }
    const float4* sv = (const float4*)(vp + (size_t)vr_ * DH + vc * 16);
#pragma unroll
    for (int g = 0; g < 4; ++g) vv4[g] = sv[g];
  }

  auto writeKV = [&](int buf) {
    int KB = buf * 4096, VB = 8192 + buf * 4096;
#pragma unroll
    for (int pp = 0; pp < 2; ++pp) {
      int row = pp * 32 + krr;
      float4 a = kr[2 * pp], c = kr[2 * pp + 1];
      uint4 u;
      u.x = packbf(a.x, a.y);
      u.y = packbf(a.z, a.w);
      u.z = packbf(c.x, c.y);
      u.w = packbf(c.z, c.w);
      *(uint4*)&smem[KB + row * 64 + 8 * (kslot ^ (row & 7))] = u;
    }
#pragma unroll
    for (int g = 0; g < 4; ++g) {
      float e[4] = {vv4[g].x, vv4[g].y, vv4[g].z, vv4[g].w};
#pragma unroll
      for (int j2 = 0; j2 < 4; ++j2) {
        int d = vc * 16 + g * 4 + j2;
        smem[VB + d * 64 + (vr_ ^ (8 * (d & 7)))] = (unsigned short)f2bf1(e[j2]);
      }
    }
  };
  writeKV(0);
  __syncthreads();

  f32x16 oT0, oT1;
#pragma unroll
  for (int i = 0; i < 16; ++i) { oT0[i] = 0.f; oT1[i] = 0.f; }
  float m_s = -1e30f, l_s = 0.f;
  int cur = 0;

  for (int kt = 0; kt < 64; ++kt) {
    // T14: issue next tile's global loads before compute
    if (kt < 63) {
      const float* kp = kh + bhb + (size_t)((kt + 1) * 64) * DH;
      const float* vp = vh + bhb + (size_t)((kt + 1) * 64) * DH;
#pragma unroll
      for (int pp = 0; pp < 2; ++pp) {
        const float4* s = (const float4*)(kp + (size_t)(pp * 32 + krr) * DH + kslot * 8);
        kr[2 * pp] = s[0];
        kr[2 * pp + 1] = s[1];
      }
      const float4* sv = (const float4*)(vp + (size_t)vr_ * DH + vc * 16);
#pragma unroll
      for (int g = 0; g < 4; ++g) vv4[g] = sv[g];
    }
    const int KB = cur * 4096, VB = 8192 + cur * 4096;
    // ---- S^T = K . Q^T  (rows = kv 0..63, cols = q of this wave)
    f32x16 sT0, sT1;
#pragma unroll
    for (int i = 0; i < 16; ++i) { sT0[i] = 0.f; sT1[i] = 0.f; }
#pragma unroll
    for (int ks = 0; ks < 4; ++ks) {
      int row0 = lq, row1 = 32 + lq;
      bf16x8 a0 = *(bf16x8*)&smem[KB + row0 * 64 + ((16 * ks + 8 * hi) ^ (8 * (row0 & 7)))];
      bf16x8 a1 = *(bf16x8*)&smem[KB + row1 * 64 + ((16 * ks + 8 * hi) ^ (8 * (row1 & 7)))];
      sT0 = __builtin_amdgcn_mfma_f32_32x32x16_bf16(a0, qf[ks], sT0, 0, 0, 0);
      sT1 = __builtin_amdgcn_mfma_f32_32x32x16_bf16(a1, qf[ks], sT1, 0, 0, 0);
    }
    // ---- online softmax; lane holds 32 kv values of one q-row (partner l^32 other 32)
    float p[32];
    float mo = -1e30f;
#pragma unroll
    for (int i = 0; i < 16; ++i) mo = fmaxf(mo, fmaxf(sT0[i], sT1[i]));
    mo = fmaxf(mo, __shfl_xor(mo, 32));
    float mn = fmaxf(m_s, mo);
    float alpha = __expf(m_s - mn);
    m_s = mn;
    float rs = 0.f;
#pragma unroll
    for (int i = 0; i < 16; ++i) {
      float p0 = __expf(sT0[i] - mn);
      float p1 = __expf(sT1[i] - mn);
      p[i] = p0;
      p[16 + i] = p1;
      rs += p0 + p1;
    }
    rs += __shfl_xor(rs, 32);
    l_s = l_s * alpha + rs;
#pragma unroll
    for (int i = 0; i < 16; ++i) { oT0[i] *= alpha; oT1[i] *= alpha; }
    // ---- P^T B-frags in-register (pack bf16 + cross-half shuffle)
    bf16x8 pf[4];
#pragma unroll
    for (int ks = 0; ks < 4; ++ks) {
      int base = (ks >> 1) * 16 + 8 * (ks & 1);
      unsigned eL0 = packbf(p[base + 0], p[base + 1]);
      unsigned eL1 = packbf(p[base + 2], p[base + 3]);
      unsigned eH0 = packbf(p[base + 4], p[base + 5]);
      unsigned eH1 = packbf(p[base + 6], p[base + 7]);
      unsigned z0 = hi ? eL0 : eH0;
      unsigned z1 = hi ? eL1 : eH1;
      unsigned r0 = (unsigned)__shfl_xor((int)z0, 32);
      unsigned r1 = (unsigned)__shfl_xor((int)z1, 32);
      union { unsigned u[4]; bf16x8 v; } U;
      if (hi) { U.u[0] = r0; U.u[1] = r1; U.u[2] = eH0; U.u[3] = eH1; }
      else    { U.u[0] = eL0; U.u[1] = eL1; U.u[2] = r0; U.u[3] = r1; }
      pf[ks] = U.v;
    }
    // ---- O^T += V^T . P^T
#pragma unroll
    for (int ks = 0; ks < 4; ++ks) {
      int row0 = lq, row1 = 32 + lq;
      bf16x8 v0 = *(bf16x8*)&smem[VB + row0 * 64 + ((16 * ks + 8 * hi) ^ (8 * (row0 & 7)))];
      bf16x8 v1 = *(bf16x8*)&smem[VB + row1 * 64 + ((16 * ks + 8 * hi) ^ (8 * (row1 & 7)))];
      oT0 = __builtin_amdgcn_mfma_f32_32x32x16_bf16(v0, pf[ks], oT0, 0, 0, 0);
      oT1 = __builtin_amdgcn_mfma_f32_32x32x16_bf16(v1, pf[ks], oT1, 0, 0, 0);
    }
    if (kt < 63) writeKV(cur ^ 1);
    __syncthreads();
    cur ^= 1;
  }

  // ---- epilogue: O/l + v skip, head-LN over d (lane holds 32 d, partner other 32)
  float inv = 1.f / l_s;
  float ov[32];
#pragma unroll
  for (int i = 0; i < 16; ++i) { ov[i] = oT0[i] * inv; ov[16 + i] = oT1[i] * inv; }
  int n = qt * 128 + w * 32 + lq;
  const float* vrow = vh + bhb + (size_t)n * DH;
#pragma unroll
  for (int dt = 0; dt < 2; ++dt)
#pragma unroll
    for (int g = 0; g < 4; ++g) {
      const float* s = vrow + dt * 32 + g * 8 + hi * 4;
#pragma unroll
      for (int r = 0; r < 4; ++r) ov[dt * 16 + g * 4 + r] += s[r];
    }
  float s1 = 0.f, s2 = 0.f;
#pragma unroll
  for (int i = 0; i < 32; ++i) { s1 += ov[i]; s2 += ov[i] * ov[i]; }
  s1 += __shfl_xor(s1, 32);
  s2 += __shfl_xor(s2, 32);
  float mu = s1 * (1.f / 64.f);
  float va = s2 * (1.f / 64.f) - mu * mu;
  float ri = rsqrtf(va + 1e-6f);
  float* ob = att + (size_t)b * INNER * NTOK + n;
#pragma unroll
  for (int dt = 0; dt < 2; ++dt)
#pragma unroll
    for (int g = 0; g < 4; ++g)
#pragma unroll
      for (int r = 0; r < 4; ++r) {
        int d = dt * 32 + g * 8 + hi * 4 + r;
        float y = (ov[dt * 16 + g * 4 + r] - mu) * ri * nw[d] + nb[d];
        ob[(size_t)(d * 4 + head) * NTOK] = y;
      }
}

// ---------------------------------------------------------------- kernel 7
__global__ __launch_bounds__(256) void k_ln2d(const float* __restrict__ pw,
    const float* __restrict__ lnw, const float* __restrict__ lnb,
    float* __restrict__ out) {
  __shared__ float sh1[4][64], sh2[4][64];
  int b = blockIdx.x >> 6, nt = blockIdx.x & 63;
  int ln = threadIdx.x & 63, part = threadIdx.x >> 6;
  int n = nt * 64 + ln;
  const float* base = pw + (size_t)b * DIM * NTOK + n;
  float a1 = 0.f, a2 = 0.f;
  for (int c = part * 32; c < part * 32 + 32; ++c) {
    float v = base[(size_t)c * NTOK];
    a1 += v;
    a2 += v * v;
  }
  sh1[part][ln] = a1;
  sh2[part][ln] = a2;
  __syncthreads();
  float s1 = sh1[0][ln] + sh1[1][ln] + sh1[2][ln] + sh1[3][ln];
  float s2 = sh2[0][ln] + sh2[1][ln] + sh2[2][ln] + sh2[3][ln];
  float mu = s1 * (1.f / 128.f);
  float var = s2 * (1.f / 128.f) - mu * mu;
  float ri = rsqrtf(var + 1e-6f);
  float* ob = out + (size_t)b * DIM * NTOK + n;
  for (int c = part * 32; c < part * 32 + 32; ++c) {
    float v = base[(size_t)c * NTOK];
    ob[(size_t)c * NTOK] = (v - mu) * ri * lnw[c] + lnb[c];
  }
}

// ----------------------------------------------------------------
extern "C" void kernel_launch(void* const* d_in, const int* in_sizes, int n_in,
                              void* d_out, int out_size, void* d_ws,
                              size_t ws_size, hipStream_t stream) {
  const float* x      = (const float*)d_in[0];
  const float* pe_w   = (const float*)d_in[1];
  const float* pe_b   = (const float*)d_in[2];
  const float* qkv_dw = (const float*)d_in[3];
  const float* qkv_pw = (const float*)d_in[4];
  const float* out_dw = (const float*)d_in[5];
  const float* out_pw = (const float*)d_in[6];
  const float* nq_w   = (const float*)d_in[7];
  const float* nq_b   = (const float*)d_in[8];
  const float* nk_w   = (const float*)d_in[9];
  const float* nk_b   = (const float*)d_in[10];
  const float* no_w   = (const float*)d_in[11];
  const float* no_b   = (const float*)d_in[12];
  const float* ln_w   = (const float*)d_in[13];
  const float* ln_b   = (const float*)d_in[14];

  float* ws = (float*)d_ws;
  float* dwy  = ws;                    // [2][128][4096]
  float* qhb  = ws + (1u << 20);       // [8][4096][64]
  float* khb  = qhb + (1u << 21);
  float* vhb  = khb + (1u << 21);
  float* att  = vhb + (1u << 21);      // [2][256][4096]
  float* dwy2 = qhb;                   // reuse (q dead after attention)
  float* pwout = dwy;                  // reuse (dwy dead after qkv gemm)
  float* outp = (float*)d_out;

  k_pe_dw<<<dim3(BB * DIM), dim3(256), 0, stream>>>(x, pe_w, pe_b, qkv_dw, dwy);
  k_gemm<128, 0><<<dim3(BB * 12 * 64), dim3(256), 0, stream>>>(
      qkv_pw, dwy, qhb, khb, vhb, 12);
  k_lnqk<<<dim3(16384), dim3(256), 0, stream>>>(qhb, khb, nq_w, nq_b, nk_w, nk_b);
  k_attn_mfma<<<dim3(256), dim3(256), 0, stream>>>(qhb, khb, vhb, no_w, no_b, att);
  k_dw<<<dim3(BB * INNER), dim3(256), 0, stream>>>(att, out_dw, dwy2, INNER - 1);
  k_gemm<256, 1><<<dim3(BB * 2 * 64), dim3(256), 0, stream>>>(
      out_pw, dwy2, pwout, nullptr, nullptr, 2);
  k_ln2d<<<dim3(BB * 64), dim3(256), 0, stream>>>(pwout, ln_w, ln_b, outp);
}

// Round 3
// 258.529 us; speedup vs baseline: 3.3137x; 1.1112x over previous
//
#include <hip/hip_runtime.h>

#define BB 2
#define NTOK 4096
#define DIM 128
#define INNER 256
#define HEADS 4
#define DH 64
#define QS 0.18033688011112043f  // 0.125 * log2(e)

typedef unsigned short u16;
typedef __attribute__((ext_vector_type(8))) short bf16x8;
typedef __attribute__((ext_vector_type(16))) float f32x16;

__device__ inline unsigned f2bf1(float f) {
  union { float f; unsigned u; } a; a.f = f;
  return (a.u + 0x7fffu + ((a.u >> 16) & 1u)) >> 16;  // RNE
}
__device__ inline float bf2f(u16 h) {
  union { unsigned u; float f; } a; a.u = ((unsigned)h) << 16;
  return a.f;
}
__device__ inline unsigned cvtpk(float lo, float hi) {
  unsigned r;
  asm("v_cvt_pk_bf16_f32 %0, %1, %2" : "=v"(r) : "v"(lo), "v"(hi));
  return r;
}

// ---------------------------------------------------------------- kernel 1
// x + pos-enc, depthwise 3x3 (SAME); writes bf16 n-major [b][n][128]
__global__ __launch_bounds__(256) void k_pe_dw(const float* __restrict__ x,
    const float* __restrict__ pew, const float* __restrict__ peb,
    const float* __restrict__ dw, u16* __restrict__ out) {
  int bc = blockIdx.x;              // b*128 + c
  int b = bc >> 7, c = bc & 127;
  float s0 = pew[c * 2 + 0] * (1.0f / 63.0f);
  float s1 = pew[c * 2 + 1] * (1.0f / 63.0f);
  float pb = peb[c];
  float w[9];
#pragma unroll
  for (int q = 0; q < 9; ++q) w[q] = dw[c * 9 + q];
  const float* xb = x + (size_t)bc * NTOK;
  u16* ob = out + (size_t)b * NTOK * DIM + c;
  for (int p = threadIdx.x; p < NTOK; p += 256) {
    int i = p >> 6, j = p & 63;
    float acc = 0.f;
#pragma unroll
    for (int di = 0; di < 3; ++di) {
      int ii = i + di - 1;
      if ((unsigned)ii < 64u) {
#pragma unroll
        for (int dj = 0; dj < 3; ++dj) {
          int jj = j + dj - 1;
          if ((unsigned)jj < 64u) {
            float xv = xb[ii * 64 + jj] + ii * s0 + jj * s1 + pb;
            acc += xv * w[di * 3 + dj];
          }
        }
      }
    }
    ob[(size_t)p * DIM] = (u16)f2bf1(acc);
  }
}

// ---------------------------------------------------------------- kernel 5
// depthwise 3x3 on att fp32 [b][256][n]; writes bf16 n-major [b][n][256]
__global__ __launch_bounds__(256) void k_dw(const float* __restrict__ x,
    const float* __restrict__ dw, u16* __restrict__ out) {
  int bc = blockIdx.x;
  int b = bc >> 8, c = bc & 255;
  float w[9];
#pragma unroll
  for (int q = 0; q < 9; ++q) w[q] = dw[c * 9 + q];
  const float* xb = x + (size_t)bc * NTOK;
  u16* ob = out + (size_t)b * NTOK * INNER + c;
  for (int p = threadIdx.x; p < NTOK; p += 256) {
    int i = p >> 6, j = p & 63;
    float acc = 0.f;
#pragma unroll
    for (int di = 0; di < 3; ++di) {
      int ii = i + di - 1;
      if ((unsigned)ii < 64u) {
#pragma unroll
        for (int dj = 0; dj < 3; ++dj) {
          int jj = j + dj - 1;
          if ((unsigned)jj < 64u) acc += xb[ii * 64 + jj] * w[di * 3 + dj];
        }
      }
    }
    ob[(size_t)p * INNER] = (u16)f2bf1(acc);
  }
}

// ---------------------------------------------------------------- kernels 2/6
// MFMA bf16 GEMM: C[M,4096] = W[M,K](fp32) @ Yb^T, Yb is [b][4096][K] bf16.
// 128x128 tile, 4 waves (2x2), 32x32x16 MFMA, BK=64, XOR-swizzled LDS.
// EPI 0 (qkv, M=768): part0/1 -> qhb/khb fp32 head rows [bh*4096+n][64],
//                     part2 -> vtb bf16 [bh][d][n].
// EPI 1 (out, M=128): pwout fp32 [b][m][4096].
template <int K, int EPI>
__global__ __launch_bounds__(256) void k_gemm_bf(
    const float* __restrict__ W, const u16* __restrict__ Yb,
    float* __restrict__ q_o, float* __restrict__ k_o,
    u16* __restrict__ v_t, int Mtiles) {
  __shared__ u16 Wl[128 * 64];
  __shared__ u16 Yl[128 * 64];
  int gid = blockIdx.x;
  int nt = gid & 31;
  int mt = (gid >> 5) % Mtiles;
  int b = gid / (32 * Mtiles);
  int t = threadIdx.x;
  int w = t >> 6, l = t & 63;
  int wm = w >> 1, wn = w & 1;
  int hi = l >> 5, lq = l & 31;

  f32x16 acc[2][2];
#pragma unroll
  for (int fm = 0; fm < 2; ++fm)
#pragma unroll
    for (int fn = 0; fn < 2; ++fn)
#pragma unroll
      for (int r = 0; r < 16; ++r) acc[fm][fn][r] = 0.f;

  int sr = t >> 1, skoff = (t & 1) * 32;
  const float* Wb = W + (size_t)(mt * 128 + sr) * K;
  const u16* Yrow = Yb + ((size_t)(b * NTOK) + nt * 128 + sr) * K;

  for (int k0 = 0; k0 < K; k0 += 64) {
#pragma unroll
    for (int jj = 0; jj < 4; ++jj) {
      int kk = skoff + jj * 8;
      float4 f0 = *(const float4*)(Wb + k0 + kk);
      float4 f1 = *(const float4*)(Wb + k0 + kk + 4);
      uint4 u;
      u.x = cvtpk(f0.x, f0.y); u.y = cvtpk(f0.z, f0.w);
      u.z = cvtpk(f1.x, f1.y); u.w = cvtpk(f1.z, f1.w);
      *(uint4*)&Wl[sr * 64 + 8 * (((kk >> 3)) ^ (sr & 7))] = u;
      uint4 yv = *(const uint4*)(Yrow + k0 + kk);
      *(uint4*)&Yl[sr * 64 + 8 * (((kk >> 3)) ^ (sr & 7))] = yv;
    }
    __syncthreads();
#pragma unroll
    for (int ks = 0; ks < 4; ++ks) {
      bf16x8 aF[2], bF[2];
#pragma unroll
      for (int fm = 0; fm < 2; ++fm) {
        int row = wm * 64 + fm * 32 + lq;
        aF[fm] = *(bf16x8*)&Wl[row * 64 + 8 * ((2 * ks + hi) ^ (row & 7))];
      }
#pragma unroll
      for (int fn = 0; fn < 2; ++fn) {
        int row = wn * 64 + fn * 32 + lq;
        bF[fn] = *(bf16x8*)&Yl[row * 64 + 8 * ((2 * ks + hi) ^ (row & 7))];
      }
#pragma unroll
      for (int fm = 0; fm < 2; ++fm)
#pragma unroll
        for (int fn = 0; fn < 2; ++fn)
          acc[fm][fn] = __builtin_amdgcn_mfma_f32_32x32x16_bf16(
              aF[fm], bF[fn], acc[fm][fn], 0, 0, 0);
    }
    __syncthreads();
  }

#pragma unroll
  for (int fm = 0; fm < 2; ++fm)
#pragma unroll
    for (int fn = 0; fn < 2; ++fn)
#pragma unroll
      for (int reg = 0; reg < 16; ++reg) {
        int rl = (reg & 3) + 8 * (reg >> 2) + 4 * hi;
        int o = mt * 128 + wm * 64 + fm * 32 + rl;
        int n = nt * 128 + wn * 64 + fn * 32 + lq;
        float val = acc[fm][fn][reg];
        if (EPI == 0) {
          int part = o >> 8, rr = o & 255;
          int head = rr & 3, d = rr >> 2;
          if (part == 0)
            q_o[((size_t)(b * HEADS + head) * NTOK + n) * DH + d] = val;
          else if (part == 1)
            k_o[((size_t)(b * HEADS + head) * NTOK + n) * DH + d] = val;
          else
            v_t[((size_t)(b * HEADS + head) * DH + d) * NTOK + n] =
                (u16)f2bf1(val);
        } else {
          q_o[((size_t)(b * DIM) + o) * NTOK + n] = val;
        }
      }
}

// ---------------------------------------------------------------- kernel 3
// per-head LN over d for q,k; writes bf16 IN PLACE (row stride 128 u16).
// q additionally scaled by QS (0.125*log2e) for exp2-domain softmax.
__global__ __launch_bounds__(256) void k_lnqk(float* __restrict__ qh,
    float* __restrict__ kh, const float* __restrict__ nqw,
    const float* __restrict__ nqb, const float* __restrict__ nkw,
    const float* __restrict__ nkb) {
  int row = blockIdx.x * 4 + (threadIdx.x >> 6);  // 0 .. 65535
  int lane = threadIdx.x & 63;
  int buf = row >> 15;           // 0 = q, 1 = k
  int r = row & 32767;           // bh*4096 + n
  int head = (r >> 12) & 3;
  float* base = (buf ? kh : qh) + (size_t)r * DH;
  const float* wp = (buf ? nkw : nqw) + head * DH;
  const float* bp = (buf ? nkb : nqb) + head * DH;
  float v = base[lane];
  float s1 = v, s2 = v * v;
#pragma unroll
  for (int off = 1; off < 64; off <<= 1) {
    s1 += __shfl_xor(s1, off);
    s2 += __shfl_xor(s2, off);
  }
  float mu = s1 * (1.f / 64.f);
  float var = s2 * (1.f / 64.f) - mu * mu;
  float y = (v - mu) * rsqrtf(var + 1e-6f) * wp[lane] + bp[lane];
  if (buf == 0) y *= QS;
  u16* bb = (u16*)base;          // row-local in-place: safe
  bb[lane] = (u16)f2bf1(y);
}

// ---------------------------------------------------------------- kernel 4
// MFMA flash attention, 8 waves: wave (qg, half) does q-group qg (32 q) over
// kv half (2048). K/V^T bf16 tiles single-buffered per half in LDS (T14
// async-stage); Q frags direct from global. Partial (O,m,l) merged via LDS.
// Epilogue: O/l + v skip (bf16 V^T), head-LN, scatter [b][d*4+head][n].
__global__ __launch_bounds__(512, 2) void k_attn2(
    const u16* __restrict__ qb, const u16* __restrict__ kb,
    const u16* __restrict__ vtb, const float* __restrict__ now,
    const float* __restrict__ nob, float* __restrict__ att) {
  __shared__ __align__(16) u16 kvbuf[16384];  // [half][K 4096 | V 4096]
  __shared__ float mlm[256], mll[256];
  __shared__ float nw[DH], nb[DH];
  const int bh = blockIdx.x >> 5, qt = blockIdx.x & 31;
  const int b = bh >> 2, head = bh & 3;
  const int t = threadIdx.x;
  const int w = t >> 6, l = t & 63;
  const int qg = w & 3, half = w >> 2;
  const int hi = l >> 5, lq = l & 31;
  if (t < DH) { nw[t] = now[head * DH + t]; nb[t] = nob[head * DH + t]; }

  const int q0 = qt * 128 + qg * 32;
  const u16* qrow = qb + (size_t)(bh * NTOK + q0 + lq) * 128;  // stride 128 u16
  bf16x8 qf[4];
#pragma unroll
  for (int ks = 0; ks < 4; ++ks)
    qf[ks] = *(const bf16x8*)(qrow + 16 * ks + 8 * hi);

  // staging coords: threads [sh*256, sh*256+256) stage half sh
  const int st = t & 255, sh = t >> 8;
  const int r0s = st >> 3, g0s = st & 7;          // granule idx st
  const int r1s = (st + 256) >> 3, g1s = st & 7;  // granule idx st+256
  const u16* kbase = kb + (size_t)(bh * NTOK) * 128;
  const u16* vbase = vtb + (size_t)(bh * DH) * NTOK;
  uint4 kr0, kr1, vr0, vr1;

  auto loadTile = [&](int s) {
    int kvt = sh * 32 + s;
    kr0 = *(const uint4*)(kbase + (size_t)(kvt * 64 + r0s) * 128 + g0s * 8);
    kr1 = *(const uint4*)(kbase + (size_t)(kvt * 64 + r1s) * 128 + g1s * 8);
    vr0 = *(const uint4*)(vbase + (size_t)r0s * NTOK + kvt * 64 + g0s * 8);
    vr1 = *(const uint4*)(vbase + (size_t)r1s * NTOK + kvt * 64 + g1s * 8);
  };
  loadTile(0);

  f32x16 oT0, oT1;
#pragma unroll
  for (int i = 0; i < 16; ++i) { oT0[i] = 0.f; oT1[i] = 0.f; }
  float m_s = -1e30f, l_s = 0.f;

  const u16* KL = kvbuf + half * 8192;
  const u16* VL = KL + 4096;

  for (int s = 0; s < 32; ++s) {
    __syncthreads();  // readers done with tile s-1
    *(uint4*)&kvbuf[sh * 8192 + r0s * 64 + 8 * (g0s ^ (r0s & 7))] = kr0;
    *(uint4*)&kvbuf[sh * 8192 + r1s * 64 + 8 * (g1s ^ (r1s & 7))] = kr1;
    *(uint4*)&kvbuf[sh * 8192 + 4096 + r0s * 64 + 8 * (g0s ^ (r0s & 7))] = vr0;
    *(uint4*)&kvbuf[sh * 8192 + 4096 + r1s * 64 + 8 * (g1s ^ (r1s & 7))] = vr1;
    __syncthreads();  // tile s visible
    if (s < 31) loadTile(s + 1);  // in flight under compute (drained next bar)

    // ---- S^T = K . Q^T
    f32x16 sT0, sT1;
#pragma unroll
    for (int i = 0; i < 16; ++i) { sT0[i] = 0.f; sT1[i] = 0.f; }
#pragma unroll
    for (int ks = 0; ks < 4; ++ks) {
      bf16x8 a0 = *(bf16x8*)&KL[lq * 64 + 8 * ((2 * ks + hi) ^ (lq & 7))];
      bf16x8 a1 = *(bf16x8*)&KL[(32 + lq) * 64 + 8 * ((2 * ks + hi) ^ (lq & 7))];
      sT0 = __builtin_amdgcn_mfma_f32_32x32x16_bf16(a0, qf[ks], sT0, 0, 0, 0);
      sT1 = __builtin_amdgcn_mfma_f32_32x32x16_bf16(a1, qf[ks], sT1, 0, 0, 0);
    }
    // ---- online softmax (exp2 domain); lane owns q = q0+lq
    float mo = fmaxf(sT0[0], sT1[0]);
#pragma unroll
    for (int i = 1; i < 16; ++i) mo = fmaxf(mo, fmaxf(sT0[i], sT1[i]));
    mo = fmaxf(mo, __shfl_xor(mo, 32));
    float mn = fmaxf(m_s, mo);
    float alpha = exp2f(m_s - mn);
    m_s = mn;
    float p[32];
    float rs = 0.f;
#pragma unroll
    for (int i = 0; i < 16; ++i) {
      float p0 = exp2f(sT0[i] - mn);
      float p1 = exp2f(sT1[i] - mn);
      p[i] = p0; p[16 + i] = p1;
      rs += p0 + p1;
    }
    rs += __shfl_xor(rs, 32);
    l_s = l_s * alpha + rs;
#pragma unroll
    for (int i = 0; i < 16; ++i) { oT0[i] *= alpha; oT1[i] *= alpha; }
    // ---- P^T B-frags in-register
    bf16x8 pf[4];
#pragma unroll
    for (int ks = 0; ks < 4; ++ks) {
      int base = (ks >> 1) * 16 + 8 * (ks & 1);
      unsigned eL0 = cvtpk(p[base + 0], p[base + 1]);
      unsigned eL1 = cvtpk(p[base + 2], p[base + 3]);
      unsigned eH0 = cvtpk(p[base + 4], p[base + 5]);
      unsigned eH1 = cvtpk(p[base + 6], p[base + 7]);
      unsigned z0 = hi ? eL0 : eH0;
      unsigned z1 = hi ? eL1 : eH1;
      unsigned rr0 = (unsigned)__shfl_xor((int)z0, 32);
      unsigned rr1 = (unsigned)__shfl_xor((int)z1, 32);
      union { unsigned u[4]; bf16x8 v; } U;
      if (hi) { U.u[0] = rr0; U.u[1] = rr1; U.u[2] = eH0; U.u[3] = eH1; }
      else    { U.u[0] = eL0; U.u[1] = eL1; U.u[2] = rr0; U.u[3] = rr1; }
      pf[ks] = U.v;
    }
    // ---- O^T += V^T . P^T
#pragma unroll
    for (int ks = 0; ks < 4; ++ks) {
      bf16x8 v0 = *(bf16x8*)&VL[lq * 64 + 8 * ((2 * ks + hi) ^ (lq & 7))];
      bf16x8 v1 = *(bf16x8*)&VL[(32 + lq) * 64 + 8 * ((2 * ks + hi) ^ (lq & 7))];
      oT0 = __builtin_amdgcn_mfma_f32_32x32x16_bf16(v0, pf[ks], oT0, 0, 0, 0);
      oT1 = __builtin_amdgcn_mfma_f32_32x32x16_bf16(v1, pf[ks], oT1, 0, 0, 0);
    }
  }

  // ---- merge halves via LDS (layout [qg][i][lane] - conflict-free)
  __syncthreads();
  float* mrg = (float*)kvbuf;
  if (half == 1) {
    float* mg = mrg + qg * 2048;
#pragma unroll
    for (int i = 0; i < 16; ++i) {
      mg[i * 64 + l] = oT0[i];
      mg[(16 + i) * 64 + l] = oT1[i];
    }
    mlm[qg * 64 + l] = m_s;
    mll[qg * 64 + l] = l_s;
  }
  __syncthreads();
  if (half == 0) {
    const float* mg = mrg + qg * 2048;
    float m1 = mlm[qg * 64 + l], l1 = mll[qg * 64 + l];
    float M = fmaxf(m_s, m1);
    float a0 = exp2f(m_s - M), a1 = exp2f(m1 - M);
    float L = l_s * a0 + l1 * a1;
    float inv = 1.f / L;
    float ov[32];
#pragma unroll
    for (int i = 0; i < 16; ++i) {
      ov[i] = (oT0[i] * a0 + mg[i * 64 + l] * a1) * inv;
      ov[16 + i] = (oT1[i] * a0 + mg[(16 + i) * 64 + l] * a1) * inv;
    }
    int n = q0 + lq;
    // skip: += v (bf16 V^T)
#pragma unroll
    for (int dt = 0; dt < 2; ++dt)
#pragma unroll
      for (int g = 0; g < 4; ++g)
#pragma unroll
        for (int r = 0; r < 4; ++r) {
          int d = dt * 32 + g * 8 + hi * 4 + r;
          ov[dt * 16 + g * 4 + r] +=
              bf2f(vtb[((size_t)(bh * DH) + d) * NTOK + n]);
        }
    float s1 = 0.f, s2 = 0.f;
#pragma unroll
    for (int i = 0; i < 32; ++i) { s1 += ov[i]; s2 += ov[i] * ov[i]; }
    s1 += __shfl_xor(s1, 32);
    s2 += __shfl_xor(s2, 32);
    float mu = s1 * (1.f / 64.f);
    float va = s2 * (1.f / 64.f) - mu * mu;
    float ri = rsqrtf(va + 1e-6f);
    float* ob = att + (size_t)b * INNER * NTOK + n;
#pragma unroll
    for (int dt = 0; dt < 2; ++dt)
#pragma unroll
      for (int g = 0; g < 4; ++g)
#pragma unroll
        for (int r = 0; r < 4; ++r) {
          int d = dt * 32 + g * 8 + hi * 4 + r;
          float y = (ov[dt * 16 + g * 4 + r] - mu) * ri * nw[d] + nb[d];
          ob[(size_t)(d * 4 + head) * NTOK] = y;
        }
  }
}

// ---------------------------------------------------------------- kernel 7
__global__ __launch_bounds__(256) void k_ln2d(const float* __restrict__ pw,
    const float* __restrict__ lnw, const float* __restrict__ lnb,
    float* __restrict__ out) {
  __shared__ float sh1[4][64], sh2[4][64];
  int b = blockIdx.x >> 6, nt = blockIdx.x & 63;
  int ln = threadIdx.x & 63, part = threadIdx.x >> 6;
  int n = nt * 64 + ln;
  const float* base = pw + (size_t)b * DIM * NTOK + n;
  float a1 = 0.f, a2 = 0.f;
  for (int c = part * 32; c < part * 32 + 32; ++c) {
    float v = base[(size_t)c * NTOK];
    a1 += v;
    a2 += v * v;
  }
  sh1[part][ln] = a1;
  sh2[part][ln] = a2;
  __syncthreads();
  float s1 = sh1[0][ln] + sh1[1][ln] + sh1[2][ln] + sh1[3][ln];
  float s2 = sh2[0][ln] + sh2[1][ln] + sh2[2][ln] + sh2[3][ln];
  float mu = s1 * (1.f / 128.f);
  float var = s2 * (1.f / 128.f) - mu * mu;
  float ri = rsqrtf(var + 1e-6f);
  float* ob = out + (size_t)b * DIM * NTOK + n;
  for (int c = part * 32; c < part * 32 + 32; ++c) {
    float v = base[(size_t)c * NTOK];
    ob[(size_t)c * NTOK] = (v - mu) * ri * lnw[c] + lnb[c];
  }
}

// ----------------------------------------------------------------
extern "C" void kernel_launch(void* const* d_in, const int* in_sizes, int n_in,
                              void* d_out, int out_size, void* d_ws,
                              size_t ws_size, hipStream_t stream) {
  const float* x      = (const float*)d_in[0];
  const float* pe_w   = (const float*)d_in[1];
  const float* pe_b   = (const float*)d_in[2];
  const float* qkv_dw = (const float*)d_in[3];
  const float* qkv_pw = (const float*)d_in[4];
  const float* out_dw = (const float*)d_in[5];
  const float* out_pw = (const float*)d_in[6];
  const float* nq_w   = (const float*)d_in[7];
  const float* nq_b   = (const float*)d_in[8];
  const float* nk_w   = (const float*)d_in[9];
  const float* nk_b   = (const float*)d_in[10];
  const float* no_w   = (const float*)d_in[11];
  const float* no_b   = (const float*)d_in[12];
  const float* ln_w   = (const float*)d_in[13];
  const float* ln_b   = (const float*)d_in[14];

  float* ws = (float*)d_ws;
  // layout (float offsets), peak 7.5M floats = 30 MB:
  u16*   dwyb = (u16*)ws;                       // [2][4096][128] bf16 (2MB)
  float* qhb  = ws + (1u << 19);                // [8][4096][64] f32 -> bf16 in place
  float* khb  = ws + (5u << 19);                // same
  u16*   vtb  = (u16*)(ws + (9u << 19));        // [8][64][4096] bf16 (4MB)
  float* att  = ws + (11u << 19);               // [2][256][4096] f32 (8MB)
  u16*   db16 = (u16*)khb;                      // reuse (k dead after attn)
  float* pwout = qhb;                           // reuse (q dead after attn)
  float* outp = (float*)d_out;

  k_pe_dw<<<dim3(BB * DIM), dim3(256), 0, stream>>>(x, pe_w, pe_b, qkv_dw, dwyb);
  k_gemm_bf<128, 0><<<dim3(BB * 6 * 32), dim3(256), 0, stream>>>(
      qkv_pw, dwyb, qhb, khb, vtb, 6);
  k_lnqk<<<dim3(16384), dim3(256), 0, stream>>>(qhb, khb, nq_w, nq_b, nk_w, nk_b);
  k_attn2<<<dim3(256), dim3(512), 0, stream>>>(
      (const u16*)qhb, (const u16*)khb, vtb, no_w, no_b, att);
  k_dw<<<dim3(BB * INNER), dim3(256), 0, stream>>>(att, out_dw, db16);
  k_gemm_bf<256, 1><<<dim3(BB * 1 * 32), dim3(256), 0, stream>>>(
      out_pw, db16, pwout, nullptr, nullptr, 1);
  k_ln2d<<<dim3(BB * 64), dim3(256), 0, stream>>>(pwout, ln_w, ln_b, outp);
}